// Round 1
// baseline (156.109 us; speedup 1.0000x reference)
//
#include <hip/hip_runtime.h>
#include <hip/hip_bf16.h>
#include <math.h>

// spatialAttention: B=512, P=128, D=64, domain 12x12, W [64,128], out [512,128,64] f32
#define NB 512
#define NP 128
#define ND 64
#define EPSF 1e-5f
// bf16-element row stride for MFMA-read LDS arrays: 136 elems = 272 B.
// 272 % 16 == 0 -> every short8 frag access is 16B-aligned; frag-read bank
// aliasing is 2-way (free per m136).
#define SW 136

typedef __attribute__((ext_vector_type(8))) short short8;   // 8 bf16 = 4 VGPRs
typedef __attribute__((ext_vector_type(4))) float f32x4;    // MFMA accumulator

__device__ __forceinline__ short f2bf(float x) {
    __hip_bfloat16 h = __float2bfloat16(x);
    return *reinterpret_cast<short*>(&h);
}

// bin = floor(x/30) clamped to [0,11]. f64 multiply by RN64(1/30) then RN to
// f32 agrees with numpy's RN32(x/30) except w.p. ~2^-29/elem (f32 rcp-mul
// would flip ~20 bins across 16.8M elems). x >= 0 here so (int) = floor.
__device__ __forceinline__ int bin30(float x) {
    float t = (float)((double)x * (1.0 / 30.0));
    int i = (int)t;
    return i < 0 ? 0 : (i > 11 ? 11 : i);
}

__device__ __forceinline__ float fast_tanh(float x) {
    float e = __expf(2.0f * x);                    // ~1 ulp native exp
    return 1.0f - 2.0f * __builtin_amdgcn_rcpf(e + 1.0f);
}

// W as bf16 [64][128], produced by prep kernel each launch (graph-safe).
__device__ __align__(16) short g_wbf[ND * 2 * ND];

__global__ __launch_bounds__(256) void prep_w(const float* __restrict__ W) {
    int idx = blockIdx.x * 256 + threadIdx.x;     // 2048 float4
    float4 v = ((const float4*)W)[idx];
    short4 s4;
    s4.x = f2bf(v.x); s4.y = f2bf(v.y); s4.z = f2bf(v.z); s4.w = f2bf(v.w);
    *(short4*)&g_wbf[idx * 4] = s4;
}

// R6 restructure: 2 blocks per batch (rows [half*64, half*64+64)) but now
// 512 threads = 8 waves per block. LDS is unchanged (36.3 KB -> 4 blocks/CU),
// so waves/CU goes 16 -> 32 (occupancy cap 50% -> 100%). Counters showed the
// kernel latency-bound (MfmaUtil 1.7%, VALUBusy 14%, HBM 17-24%, Occ 34%):
// nothing was saturated, so double the resident waves and halve each wave's
// serial load->consume chain in phase 1.
//   phase 1: wave owns 8 rows (4 iters x 2 rows); UNNORMALIZED E = exp(w)+eps
//            (masked) -> bf16 LDS. float4 loads, 1KB/instr coalescing.
//   phase 2: wave PAIR shares a 16-row MFMA tile (rt = wave>>1); each wave
//            computes 2 of the 4 tj output-column tiles + its own (cheap,
//            duplicated) ones-MFMA row sums. Cross-wave tile sharing means
//            the old wave-local DS-ordering trick is gone: explicit barriers
//            around the E -> [wh|h] in-place overwrite.
//   phase 3: out = fast_tanh(fused @ W^T + b), W-frags from g_wbf (L2-hot),
//            2 tj tiles per wave.
__global__ __launch_bounds__(512, 8) void spatial_attn_kernel(
    const float* __restrict__ hidden,   // [B,P,D]
    const float* __restrict__ dist,     // [B,P,P]
    const float* __restrict__ bear,     // [B,P,P]
    const float* __restrict__ head,     // [B,P,P]
    const float* __restrict__ smask,    // [B,P]
    const float* __restrict__ domain,   // [12,12]
    const float* __restrict__ bias,     // [D]
    float* __restrict__ out)            // [B,P,D]
{
    __shared__ __align__(16) short s_w[64 * SW];   // 17408 B: E, then [wh|h]
    __shared__ __align__(16) short s_hT[ND * SW];  // 17408 B: s_hT[d][q] = h[q][d]
    __shared__ float s_dom[144];
    __shared__ float s_mask[NP];

    const int blk  = blockIdx.x;
    const int b    = blk >> 1;
    const int half = blk & 1;
    const int tid  = threadIdx.x;
    const int lane = tid & 63;
    const int wave = tid >> 6;          // 0..7
    const int quad = lane >> 4;
    const int l16  = lane & 15;

    // ---- issue hidden loads early (independent of the dom/mask barrier) ----
    float4 hv[4];
    int hq[4], hd[4];
    {
        const float4* hsrc = (const float4*)(hidden + (size_t)b * NP * ND);
        #pragma unroll
        for (int i = 0; i < 4; ++i) {
            int idx = i * 512 + ((tid & 15) * 32 + (tid >> 4));  // bijective
            hv[i] = hsrc[idx];
            hq[i] = idx >> 4;            // q 0..127
            hd[i] = (idx & 15) * 4;      // d 0..60
        }
    }
    if (tid < 144) s_dom[tid] = domain[tid];
    if (tid < NP)  s_mask[tid] = smask[b * NP + tid];
    __syncthreads();   // dom/mask ready for phase 1

    // ---- stage hidden^T bf16 (swizzled perm keeps transpose writes ~4-way);
    //      overlaps with phase-1 load latency, consumed after next barrier ----
    #pragma unroll
    for (int i = 0; i < 4; ++i) {
        s_hT[(hd[i] + 0) * SW + hq[i]] = f2bf(hv[i].x);
        s_hT[(hd[i] + 1) * SW + hq[i]] = f2bf(hv[i].y);
        s_hT[(hd[i] + 2) * SW + hq[i]] = f2bf(hv[i].z);
        s_hT[(hd[i] + 3) * SW + hq[i]] = f2bf(hv[i].w);
    }

    // Each lane owns 4 consecutive q of one of 2 rows per iteration.
    const int rsel = lane >> 5;           // 0 or 1: which of the 2 rows
    const int q0   = (lane & 31) * 4;     // column base within the row
    const size_t rowbase = (size_t)b * NP * NP;
    const float4 mqv = *(const float4*)&s_mask[q0];   // masks for q0..q0+3

    // ---- phase 1: unnormalized masked exp; 1KB/instr float4 streaming ----
    const int R0L1 = wave * 8;            // phase-1 local row base (of 64)
    #pragma unroll 2
    for (int j0 = 0; j0 < 8; j0 += 2) {
        const int rl = R0L1 + j0 + rsel;              // local row in s_w
        const int p  = half * 64 + rl;                // row within batch
        const size_t ro = rowbase + (size_t)p * NP + q0;
        float4 dq = *(const float4*)&dist[ro];
        float4 bq = *(const float4*)&bear[ro];
        float4 hq4 = *(const float4*)&head[ro];
        const float mp = s_mask[p];

        float hv4[4] = {hq4.x, hq4.y, hq4.z, hq4.w};
        float bv[4] = {bq.x, bq.y, bq.z, bq.w};
        float dv[4] = {dq.x, dq.y, dq.z, dq.w};
        float mv[4] = {mqv.x, mqv.y, mqv.z, mqv.w};
        short ex[4];
        #pragma unroll
        for (int c = 0; c < 4; ++c) {
            int i1 = bin30(hv4[c]), i2 = bin30(bv[c]);
            float wv = s_dom[i1 * 12 + i2] - dv[c];
            bool on = (wv > 0.0f) && (mp != 0.0f) && (mv[c] != 0.0f) && (q0 + c != p);
            ex[c] = f2bf(on ? (__expf(wv) + EPSF) : EPSF);
        }
        short4 res; res.x = ex[0]; res.y = ex[1]; res.z = ex[2]; res.w = ex[3];
        *(short4*)&s_w[rl * SW + q0] = res;           // 8B-aligned ds_write_b64
    }
    __syncthreads();   // B1: E rows (2 waves per tile) + s_hT complete

    // ---- phase 2: wh_unnorm = E @ h + ones-MFMA row sums (K=128) ----
    // wave pair (2rt, 2rt+1) shares row tile rt; each wave does 2 tj tiles.
    const int rt  = wave >> 1;            // 0..3
    const int R0L = rt * 16;              // local row base (of 64)
    const int tjh = (wave & 1) * 2;       // tj base: {0,1} or {2,3}
    const int P0  = half * 64 + R0L;      // row base within batch (of 128)

    f32x4 acc[2], accs;
    #pragma unroll
    for (int t = 0; t < 2; ++t) acc[t] = (f32x4){0.f, 0.f, 0.f, 0.f};
    accs = (f32x4){0.f, 0.f, 0.f, 0.f};

    short8 ones;
    #pragma unroll
    for (int i = 0; i < 8; ++i) ones[i] = (short)0x3F80;  // bf16 1.0

    #pragma unroll
    for (int kb = 0; kb < 4; ++kb) {
        const int ko = kb * 32 + quad * 8;
        short8 a = *(const short8*)&s_w[(R0L + l16) * SW + ko];
        accs = __builtin_amdgcn_mfma_f32_16x16x32_bf16(a, ones, accs, 0, 0, 0);
        #pragma unroll
        for (int t = 0; t < 2; ++t) {
            short8 bf = *(const short8*)&s_hT[((tjh + t) * 16 + l16) * SW + ko];
            acc[t] = __builtin_amdgcn_mfma_f32_16x16x32_bf16(a, bf, acc[t], 0, 0, 0);
        }
    }

    // C/D row = quad*4 + r; accs rows match lane-for-lane.
    float inv[4];
    #pragma unroll
    for (int r = 0; r < 4; ++r) inv[r] = 1.0f / (accs[r] + EPSF);

    __syncthreads();   // B2: pair-partner's E A-frag reads done before overwrite

    // ---- build fused rows [wh | h] in s_w ----
    #pragma unroll
    for (int t = 0; t < 2; ++t)
        #pragma unroll
        for (int r = 0; r < 4; ++r) {
            int row = R0L + quad * 4 + r;
            s_w[row * SW + (tjh + t) * 16 + l16] = f2bf(acc[t][r] * inv[r]);
        }
    // h columns from s_hT; wave copies 8 of the tile's 16 rows. b64 reads
    // (4 q per instr) quarter the 8-way-conflicted instruction count vs u16.
    #pragma unroll
    for (int i4 = 0; i4 < 2; ++i4) {
        int rbase = R0L + (wave & 1) * 8 + i4 * 4;
        int qb = half * 64 + rbase;                   // q = half*64 + local row
        short4 hcol = *(const short4*)&s_hT[lane * SW + qb];
        s_w[(rbase + 0) * SW + 64 + lane] = hcol.x;
        s_w[(rbase + 1) * SW + 64 + lane] = hcol.y;
        s_w[(rbase + 2) * SW + 64 + lane] = hcol.z;
        s_w[(rbase + 3) * SW + 64 + lane] = hcol.w;
    }
    __syncthreads();   // B3: fused rows complete

    // ---- phase 3: out = tanh(fused @ W^T + b), B-frags from g_wbf (L2) ----
    f32x4 acc2[2];
    #pragma unroll
    for (int t = 0; t < 2; ++t) acc2[t] = (f32x4){0.f, 0.f, 0.f, 0.f};

    #pragma unroll
    for (int kb = 0; kb < 4; ++kb) {
        const int ko = kb * 32 + quad * 8;
        short8 a = *(const short8*)&s_w[(R0L + l16) * SW + ko];
        #pragma unroll
        for (int t = 0; t < 2; ++t) {
            short8 bf = *(const short8*)&g_wbf[((tjh + t) * 16 + l16) * (2 * ND) + ko];
            acc2[t] = __builtin_amdgcn_mfma_f32_16x16x32_bf16(a, bf, acc2[t], 0, 0, 0);
        }
    }

    float bvals[2];
    #pragma unroll
    for (int t = 0; t < 2; ++t) bvals[t] = bias[(tjh + t) * 16 + l16];

    float* ob = out + ((size_t)b * NP + half * 64) * ND;
    #pragma unroll
    for (int t = 0; t < 2; ++t)
        #pragma unroll
        for (int r = 0; r < 4; ++r) {
            int row = R0L + quad * 4 + r;
            ob[(size_t)row * ND + (tjh + t) * 16 + l16] = fast_tanh(acc2[t][r] + bvals[t]);
        }
}

extern "C" void kernel_launch(void* const* d_in, const int* in_sizes, int n_in,
                              void* d_out, int out_size, void* d_ws, size_t ws_size,
                              hipStream_t stream) {
    const float* hidden = (const float*)d_in[0];
    const float* dist   = (const float*)d_in[1];
    const float* bear   = (const float*)d_in[2];
    const float* head   = (const float*)d_in[3];
    const float* smask  = (const float*)d_in[4];
    const float* domain = (const float*)d_in[5];
    const float* W      = (const float*)d_in[6];
    const float* bias   = (const float*)d_in[7];
    float* out = (float*)d_out;

    prep_w<<<dim3(8), dim3(256), 0, stream>>>(W);
    spatial_attn_kernel<<<dim3(NB * 2), dim3(512), 0, stream>>>(
        hidden, dist, bear, head, smask, domain, bias, out);
}